// Round 1
// baseline (4561.920 us; speedup 1.0000x reference)
//
#include <hip/hip_runtime.h>
#include <math.h>

// Problem constants (from reference)
#define TT   64
#define BBB  2048
#define TBR  (TT * BBB)   // 131072 rows
#define OBS  512
#define H1   400
#define H2   300
#define CORE 302          // H2 + clipped_reward + last_action

// Tiling
#define MROWS 16          // rows per block
#define NTHREADS 512
// LDS strides (padded to break 32-bank power-of-2 conflicts, 16B-aligned rows)
#define FS   516          // frame tile stride (516*4 % 16 == 0, 516%32=4 -> 2-way max)
#define H1S  404          // h1 tile stride
#define CS   308          // core tile stride

__global__ __launch_bounds__(NTHREADS) void autoprune_fused(
    const float* __restrict__ frame, const float* __restrict__ reward,
    const int*   __restrict__ last_action, const float* __restrict__ eps,
    const float* __restrict__ W1, const float* __restrict__ b1,
    const float* __restrict__ W2, const float* __restrict__ b2,
    const float* __restrict__ Wp, const float* __restrict__ bp,
    const float* __restrict__ Wb, const float* __restrict__ bb,
    float* __restrict__ out)
{
    __shared__ float sm_frame[MROWS * FS];   // 33.0 KB
    __shared__ float sm_h1[MROWS * H1S];     // 25.9 KB
    __shared__ float sm_core[MROWS * CS];    // 19.7 KB
    __shared__ float sm_res[MROWS][4];

    const int tid  = threadIdx.x;
    const int row0 = blockIdx.x * MROWS;

    // ---- Phase 1: stage frame tile [16 x 512] into LDS (coalesced float4) ----
    {
        const float* fbase = frame + (size_t)row0 * OBS;
        #pragma unroll
        for (int i = 0; i < (MROWS * OBS) / (NTHREADS * 4); ++i) {   // 4 iters
            int idx = tid * 4 + i * (NTHREADS * 4);                  // 0..8191
            int r = idx >> 9;
            int c = idx & 511;
            float4 v = *(const float4*)(fbase + idx);
            *(float4*)(&sm_frame[r * FS + c]) = v;
        }
        // extra core features (clipped reward, last_action)
        if (tid < MROWS) {
            int r = row0 + tid;
            float cr = fminf(fmaxf(reward[r], -1.0f), 1.0f);
            sm_core[tid * CS + 300] = cr;
            sm_core[tid * CS + 301] = (float)last_action[r];
        }
    }
    __syncthreads();

    const int rr = tid & 15;   // row within tile
    const int cw = tid >> 4;   // 0..31 column lane

    // ---- Phase 2: h1 = relu(frame @ W1^T + b1)  [16 x 400], K=512 ----
    {
        const float* fr = sm_frame + rr * FS;
        #pragma unroll
        for (int cb = 0; cb < 13; ++cb) {          // ceil(400/32)
            const int col = cb * 32 + cw;
            if (col < H1) {
                const float* w = W1 + col * OBS;
                float ax = 0.f, ay = 0.f, az = 0.f, aw = 0.f;
                #pragma unroll 4
                for (int k = 0; k < OBS; k += 4) {
                    float4 wv = *(const float4*)(w + k);
                    float4 fv = *(const float4*)(fr + k);
                    ax = fmaf(fv.x, wv.x, ax);
                    ay = fmaf(fv.y, wv.y, ay);
                    az = fmaf(fv.z, wv.z, az);
                    aw = fmaf(fv.w, wv.w, aw);
                }
                float acc = (ax + ay) + (az + aw) + b1[col];
                sm_h1[rr * H1S + col] = fmaxf(acc, 0.0f);
            }
        }
    }
    __syncthreads();

    // ---- Phase 3: h2 = relu(h1 @ W2^T + b2) -> sm_core[:, 0:300], K=400 ----
    {
        const float* h = sm_h1 + rr * H1S;
        #pragma unroll
        for (int cb = 0; cb < 10; ++cb) {          // ceil(300/32)
            const int col = cb * 32 + cw;
            if (col < H2) {
                const float* w = W2 + col * H1;
                float ax = 0.f, ay = 0.f, az = 0.f, aw = 0.f;
                #pragma unroll 4
                for (int k = 0; k < H1; k += 4) {
                    float4 wv = *(const float4*)(w + k);
                    float4 hv = *(const float4*)(h + k);
                    ax = fmaf(hv.x, wv.x, ax);
                    ay = fmaf(hv.y, wv.y, ay);
                    az = fmaf(hv.z, wv.z, az);
                    aw = fmaf(hv.w, wv.w, aw);
                }
                float acc = (ax + ay) + (az + aw) + b2[col];
                sm_core[rr * CS + col] = fmaxf(acc, 0.0f);
            }
        }
    }
    __syncthreads();

    // ---- Phase 4: head — pl = sigmoid(core @ Wp^T + bp), baseline = core @ Wb^T + bb ----
    if (tid < 64) {
        const int row = tid >> 2;
        const int o   = tid & 3;
        if (o < 3) {
            const float* w = (o == 0) ? Wp : (o == 1) ? (Wp + CORE) : Wb;
            const float* c = sm_core + row * CS;
            float acc = 0.0f;
            #pragma unroll 2
            for (int k = 0; k < CORE; ++k) acc = fmaf(c[k], w[k], acc);
            acc += (o < 2) ? bp[o] : bb[0];
            if (o < 2) acc = 1.0f / (1.0f + __expf(-acc));
            sm_res[row][o] = acc;
        }
    }
    __syncthreads();

    // ---- Phase 5: assemble [mu, sigma, baseline, action] and store ----
    if (tid < MROWS) {
        int r = row0 + tid;
        float mu = sm_res[tid][0];
        float sg = sm_res[tid][1];
        float bl = sm_res[tid][2];
        float4 o4 = make_float4(mu, sg, bl, fmaf(sg, eps[r], mu));
        *(float4*)(out + (size_t)r * 4) = o4;
    }
}

extern "C" void kernel_launch(void* const* d_in, const int* in_sizes, int n_in,
                              void* d_out, int out_size, void* d_ws, size_t ws_size,
                              hipStream_t stream) {
    const float* frame       = (const float*)d_in[0];
    const float* reward      = (const float*)d_in[1];
    const int*   last_action = (const int*)  d_in[2];
    const float* eps         = (const float*)d_in[3];
    const float* W1          = (const float*)d_in[4];
    const float* b1          = (const float*)d_in[5];
    const float* W2          = (const float*)d_in[6];
    const float* b2          = (const float*)d_in[7];
    const float* Wp          = (const float*)d_in[8];
    const float* bp          = (const float*)d_in[9];
    const float* Wb          = (const float*)d_in[10];
    const float* bb          = (const float*)d_in[11];
    float* out = (float*)d_out;

    dim3 grid(TBR / MROWS);   // 8192 blocks
    autoprune_fused<<<grid, NTHREADS, 0, stream>>>(
        frame, reward, last_action, eps, W1, b1, W2, b2, Wp, bp, Wb, bb, out);
}

// Round 2
// 486.945 us; speedup vs baseline: 9.3685x; 9.3685x over previous
//
#include <hip/hip_runtime.h>
#include <math.h>

// Problem constants
#define TBR  131072      // 64*2048 rows
#define OBS  512
#define H1N  400
#define H2N  300
#define CORE 302

// LDS strides (bf16 elems). Each = odd multiple of 8 elems (16B) so that
// row-stride ds_read_b128 fragments land on distinct 16B slots (conflict-free).
#define FR_S 520         // frame tile: 64 x 520 bf16 = 66560 B
#define H1_S 424         // h1 tile:    64 x 424 bf16 = 54272 B (K padded 400->416+)
#define CO_S 312         // core tile:  64 x 312 bf16 = 39936 B (overlays frame)

typedef __bf16 bf16x8 __attribute__((ext_vector_type(8)));
typedef float  f32x4  __attribute__((ext_vector_type(4)));

__device__ __forceinline__ bf16x8 cvt8(float4 a, float4 b) {
    bf16x8 v;
    v[0] = (__bf16)a.x; v[1] = (__bf16)a.y; v[2] = (__bf16)a.z; v[3] = (__bf16)a.w;
    v[4] = (__bf16)b.x; v[5] = (__bf16)b.y; v[6] = (__bf16)b.z; v[7] = (__bf16)b.w;
    return v;
}

__global__ __launch_bounds__(512) void autoprune_mfma(
    const float* __restrict__ frame, const float* __restrict__ reward,
    const int*   __restrict__ last_action, const float* __restrict__ eps,
    const float* __restrict__ W1, const float* __restrict__ b1,
    const float* __restrict__ W2, const float* __restrict__ b2,
    const float* __restrict__ Wp, const float* __restrict__ bp,
    const float* __restrict__ Wb, const float* __restrict__ bb,
    float* __restrict__ out)
{
    __shared__ __bf16 sm_frame[64 * FR_S];   // 66.6 KB (later reused as core)
    __shared__ __bf16 sm_h1[64 * H1_S];      // 54.3 KB
    __shared__ float  sm_res[64][4];         // 1 KB
    __bf16* sm_core = sm_frame;              // overlay: frame dead after layer 1

    const int tid = threadIdx.x;
    const int w   = tid >> 6;        // wave 0..7
    const int l   = tid & 63;
    const int l15 = l & 15;          // fragment row/col lane
    const int lg  = l >> 4;          // k-group 0..3
    const int row0 = blockIdx.x * 64;

    // ---------------- Phase 0: stage frame fp32->bf16, zero h1 K-pad ----------
    #pragma unroll
    for (int i = 0; i < 8; ++i) {
        int idx = tid + i * 512;               // 0..4095 chunk of 8 elems
        int r  = idx >> 6;
        int kc = (idx & 63) * 8;
        const float4* gp = reinterpret_cast<const float4*>(
            frame + (size_t)(row0 + r) * OBS + kc);
        float4 f0 = gp[0], f1 = gp[1];
        *reinterpret_cast<bf16x8*>(&sm_frame[r * FR_S + kc]) = cvt8(f0, f1);
    }
    if (tid < 192) {                           // zero h1 cols 400..423
        int r = tid / 3, c = 400 + (tid % 3) * 8;
        bf16x8 z;
        #pragma unroll
        for (int j = 0; j < 8; ++j) z[j] = (__bf16)0.0f;
        *reinterpret_cast<bf16x8*>(&sm_h1[r * H1_S + c]) = z;
    }
    __syncthreads();

    // ---------------- Layer 1: h1 = relu(frame @ W1^T + b1) -------------------
    // M=64 (4 Mtiles), N=400 (25 Ntiles split over 8 waves), K=512 (16 ksteps)
    {
        f32x4 acc[4][4];                       // [ti][mt]
        #pragma unroll
        for (int a = 0; a < 4; ++a)
            #pragma unroll
            for (int b = 0; b < 4; ++b) acc[a][b] = (f32x4){0.f, 0.f, 0.f, 0.f};

        for (int ks = 0; ks < 16; ++ks) {
            const int kb = ks * 32 + lg * 8;
            bf16x8 afr[4];
            #pragma unroll
            for (int mt = 0; mt < 4; ++mt)
                afr[mt] = *reinterpret_cast<const bf16x8*>(
                    &sm_frame[(mt * 16 + l15) * FR_S + kb]);
            #pragma unroll
            for (int ti = 0; ti < 4; ++ti) {
                int nt = w + ti * 8;
                if (nt < 25) {
                    const float4* wp = reinterpret_cast<const float4*>(
                        W1 + (size_t)(nt * 16 + l15) * OBS + kb);
                    bf16x8 bfr = cvt8(wp[0], wp[1]);
                    #pragma unroll
                    for (int mt = 0; mt < 4; ++mt)
                        acc[ti][mt] = __builtin_amdgcn_mfma_f32_16x16x32_bf16(
                            afr[mt], bfr, acc[ti][mt], 0, 0, 0);
                }
            }
        }
        // store h1 (C layout: col = l&15, row = lg*4 + j)
        #pragma unroll
        for (int ti = 0; ti < 4; ++ti) {
            int nt = w + ti * 8;
            if (nt < 25) {
                int c = nt * 16 + l15;
                float bias = b1[c];
                #pragma unroll
                for (int mt = 0; mt < 4; ++mt)
                    #pragma unroll
                    for (int j = 0; j < 4; ++j) {
                        int r = mt * 16 + lg * 4 + j;
                        sm_h1[r * H1_S + c] =
                            (__bf16)fmaxf(acc[ti][mt][j] + bias, 0.0f);
                    }
            }
        }
    }
    __syncthreads();

    // ---------------- Layer 2: h2 = relu(h1 @ W2^T + b2) ----------------------
    // M=64, N=304 (19 Ntiles), K=416 (13 ksteps; A zero-padded, B addr-clamped)
    {
        f32x4 acc[3][4];
        #pragma unroll
        for (int a = 0; a < 3; ++a)
            #pragma unroll
            for (int b = 0; b < 4; ++b) acc[a][b] = (f32x4){0.f, 0.f, 0.f, 0.f};

        for (int ks = 0; ks < 13; ++ks) {
            const int kb = ks * 32 + lg * 8;
            bf16x8 afr[4];
            #pragma unroll
            for (int mt = 0; mt < 4; ++mt)
                afr[mt] = *reinterpret_cast<const bf16x8*>(
                    &sm_h1[(mt * 16 + l15) * H1_S + kb]);
            const int kbw = (kb >= 400) ? 0 : kb;   // clamp: A is zero there
            #pragma unroll
            for (int ti = 0; ti < 3; ++ti) {
                int nt = w + ti * 8;
                if (nt < 19) {
                    int c  = nt * 16 + l15;
                    int cc = (c < 300) ? c : 299;   // clamp: results discarded
                    const float4* wp = reinterpret_cast<const float4*>(
                        W2 + (size_t)cc * H1N + kbw);
                    bf16x8 bfr = cvt8(wp[0], wp[1]);
                    #pragma unroll
                    for (int mt = 0; mt < 4; ++mt)
                        acc[ti][mt] = __builtin_amdgcn_mfma_f32_16x16x32_bf16(
                            afr[mt], bfr, acc[ti][mt], 0, 0, 0);
                }
            }
        }
        // store core = [relu(h2) | cr | la]  (overlays frame region)
        #pragma unroll
        for (int ti = 0; ti < 3; ++ti) {
            int nt = w + ti * 8;
            if (nt < 19) {
                int c = nt * 16 + l15;
                if (c < 300) {
                    float bias = b2[c];
                    #pragma unroll
                    for (int mt = 0; mt < 4; ++mt)
                        #pragma unroll
                        for (int j = 0; j < 4; ++j) {
                            int r = mt * 16 + lg * 4 + j;
                            sm_core[r * CO_S + c] =
                                (__bf16)fmaxf(acc[ti][mt][j] + bias, 0.0f);
                        }
                }
            }
        }
        if (tid < 64) {
            int r = row0 + tid;
            float cr = fminf(fmaxf(reward[r], -1.0f), 1.0f);
            sm_core[tid * CO_S + 300] = (__bf16)cr;
            sm_core[tid * CO_S + 301] = (__bf16)(float)last_action[r];
        }
    }
    __syncthreads();

    // ---------------- Head: pl = sigmoid(core@Wp^T+bp), baseline = core@Wb^T+bb
    if (w < 3) {                       // wave w handles output o=w for 64 rows
        const int o = w;
        const float* wv = (o == 0) ? Wp : (o == 1) ? (Wp + CORE) : Wb;
        const __bf16* cp = &sm_core[l * CO_S];
        float acc = 0.0f;
        #pragma unroll 2
        for (int k = 0; k < CORE; ++k) acc = fmaf((float)cp[k], wv[k], acc);
        acc += (o < 2) ? bp[o] : bb[0];
        if (o < 2) acc = 1.0f / (1.0f + __expf(-acc));
        sm_res[l][o] = acc;
    }
    __syncthreads();

    if (tid < 64) {
        int r = row0 + tid;
        float mu = sm_res[tid][0], sg = sm_res[tid][1], bl = sm_res[tid][2];
        float4 o4 = make_float4(mu, sg, bl, fmaf(sg, eps[r], mu));
        *reinterpret_cast<float4*>(out + (size_t)r * 4) = o4;
    }
}

extern "C" void kernel_launch(void* const* d_in, const int* in_sizes, int n_in,
                              void* d_out, int out_size, void* d_ws, size_t ws_size,
                              hipStream_t stream) {
    const float* frame       = (const float*)d_in[0];
    const float* reward      = (const float*)d_in[1];
    const int*   last_action = (const int*)  d_in[2];
    const float* eps         = (const float*)d_in[3];
    const float* W1          = (const float*)d_in[4];
    const float* b1          = (const float*)d_in[5];
    const float* W2          = (const float*)d_in[6];
    const float* b2          = (const float*)d_in[7];
    const float* Wp          = (const float*)d_in[8];
    const float* bp          = (const float*)d_in[9];
    const float* Wb          = (const float*)d_in[10];
    const float* bb          = (const float*)d_in[11];
    float* out = (float*)d_out;

    dim3 grid(TBR / 64);   // 2048 blocks, 512 threads, 1 block/CU (122 KB LDS)
    autoprune_mfma<<<grid, 512, 0, stream>>>(
        frame, reward, last_action, eps, W1, b1, W2, b2, Wp, bp, Wb, bb, out);
}

// Round 3
// 184.209 us; speedup vs baseline: 24.7649x; 2.6434x over previous
//
#include <hip/hip_runtime.h>
#include <math.h>

// Problem constants
#define TBR  131072      // 64*2048 rows
#define OBS  512
#define H1N  400
#define H2N  300
#define CORE 302

// Tiling
#define CH_K   64        // frame K-chunk
#define NCHUNK 8         // OBS / CH_K
#define CH_S   72        // chunk row stride (bf16): 144B, bank-uniform
#define H1_S   424       // h1 row stride: 848B, bank-uniform
#define CO_S   328       // core row stride: 656B, bank-uniform (K padded 302->320)
#define WH_R   64        // Whead rows start at core-row 64 (inside h1 region)

typedef __bf16 bf16x8 __attribute__((ext_vector_type(8)));
typedef float  f32x4  __attribute__((ext_vector_type(4)));

__device__ __forceinline__ bf16x8 cvt8(float4 a, float4 b) {
    bf16x8 v;
    v[0] = (__bf16)a.x; v[1] = (__bf16)a.y; v[2] = (__bf16)a.z; v[3] = (__bf16)a.w;
    v[4] = (__bf16)b.x; v[5] = (__bf16)b.y; v[6] = (__bf16)b.z; v[7] = (__bf16)b.w;
    return v;
}

// ---- weight fp32 -> bf16 pre-convert (runs every launch; deterministic) ----
__global__ void conv_weights(const float* __restrict__ W1,
                             const float* __restrict__ W2,
                             __bf16* __restrict__ ws) {
    const int n1 = (H1N * OBS) / 8;     // 25600
    const int n2 = (H2N * H1N) / 8;     // 15000
    int i = blockIdx.x * blockDim.x + threadIdx.x;
    if (i < n1) {
        const float4* p = reinterpret_cast<const float4*>(W1 + (size_t)i * 8);
        *reinterpret_cast<bf16x8*>(ws + (size_t)i * 8) = cvt8(p[0], p[1]);
    } else if (i < n1 + n2) {
        int j = i - n1;
        const float4* p = reinterpret_cast<const float4*>(W2 + (size_t)j * 8);
        *reinterpret_cast<bf16x8*>(ws + (size_t)(H1N * OBS) + (size_t)j * 8) =
            cvt8(p[0], p[1]);
    }
}

template <bool WBF16>
__global__ __launch_bounds__(512, 4) void autoprune_mfma(
    const float* __restrict__ frame, const float* __restrict__ reward,
    const int*   __restrict__ last_action, const float* __restrict__ eps,
    const float* __restrict__ W1f, const float* __restrict__ b1,
    const float* __restrict__ W2f, const float* __restrict__ b2,
    const float* __restrict__ Wp, const float* __restrict__ bp,
    const float* __restrict__ Wb, const float* __restrict__ bb,
    const __bf16* __restrict__ W1b, const __bf16* __restrict__ W2b,
    float* __restrict__ out)
{
    __shared__ __bf16 sm_chunk[2][64 * CH_S];   // 18.4 KB (frame dbuf)
    __shared__ __bf16 sm_h1[64 * H1_S];         // 54.3 KB (reused as core+Whead)
    __shared__ float  sm_res[64][4];            // 1 KB            => 73.7 KB
    __bf16* sm_core = sm_h1;

    const int tid  = threadIdx.x;
    const int w    = tid >> 6;
    const int l    = tid & 63;
    const int l15  = l & 15;
    const int lg   = l >> 4;
    const int row0 = blockIdx.x * 64;

    // staging coords: thread -> (row, 8-col chunk)
    const int sr = tid >> 3;
    const int sc = (tid & 7) * 8;
    const float* fbase = frame + (size_t)(row0 + sr) * OBS + sc;

    // ---------------- Prologue: stage chunk 0; zero h1 K-pad ------------------
    {
        float4 a = *reinterpret_cast<const float4*>(fbase);
        float4 b = *reinterpret_cast<const float4*>(fbase + 4);
        if (tid < 192) {                        // zero h1 cols 400..423
            int r = tid / 3, c = 400 + (tid % 3) * 8;
            bf16x8 z;
            #pragma unroll
            for (int j = 0; j < 8; ++j) z[j] = (__bf16)0.0f;
            *reinterpret_cast<bf16x8*>(&sm_h1[r * H1_S + c]) = z;
        }
        *reinterpret_cast<bf16x8*>(&sm_chunk[0][sr * CH_S + sc]) = cvt8(a, b);
    }
    __syncthreads();

    // ---------------- Layer 1: h1 = relu(frame @ W1^T + b1) -------------------
    // M=64 (4 mt), N=400 (25 nt over 8 waves), K=512 (8 chunks x 2 ksteps)
    {
        f32x4 acc[4][4];
        #pragma unroll
        for (int a = 0; a < 4; ++a)
            #pragma unroll
            for (int b = 0; b < 4; ++b) acc[a][b] = (f32x4){0.f, 0.f, 0.f, 0.f};

        for (int c = 0; c < NCHUNK; ++c) {
            float4 pa, pb;
            if (c < NCHUNK - 1) {               // T14: issue next-chunk loads early
                pa = *reinterpret_cast<const float4*>(fbase + (c + 1) * CH_K);
                pb = *reinterpret_cast<const float4*>(fbase + (c + 1) * CH_K + 4);
            }
            const __bf16* buf = sm_chunk[c & 1];
            #pragma unroll
            for (int ks = 0; ks < 2; ++ks) {
                const int kl = ks * 32 + lg * 8;
                bf16x8 afr[4];
                #pragma unroll
                for (int mt = 0; mt < 4; ++mt)
                    afr[mt] = *reinterpret_cast<const bf16x8*>(
                        &buf[(mt * 16 + l15) * CH_S + kl]);
                const int kg = c * CH_K + kl;
                #pragma unroll
                for (int ti = 0; ti < 4; ++ti) {
                    int nt = w + ti * 8;
                    if (nt < 25) {
                        bf16x8 bfr;
                        if constexpr (WBF16) {
                            bfr = *reinterpret_cast<const bf16x8*>(
                                W1b + (size_t)(nt * 16 + l15) * OBS + kg);
                        } else {
                            const float4* wp = reinterpret_cast<const float4*>(
                                W1f + (size_t)(nt * 16 + l15) * OBS + kg);
                            bfr = cvt8(wp[0], wp[1]);
                        }
                        #pragma unroll
                        for (int mt = 0; mt < 4; ++mt)
                            acc[ti][mt] = __builtin_amdgcn_mfma_f32_16x16x32_bf16(
                                afr[mt], bfr, acc[ti][mt], 0, 0, 0);
                    }
                }
            }
            if (c < NCHUNK - 1)
                *reinterpret_cast<bf16x8*>(
                    &sm_chunk[(c + 1) & 1][sr * CH_S + sc]) = cvt8(pa, pb);
            __syncthreads();
        }

        // C-store: col = nt*16 + l15, row = mt*16 + lg*4 + j
        #pragma unroll
        for (int ti = 0; ti < 4; ++ti) {
            int nt = w + ti * 8;
            if (nt < 25) {
                int c = nt * 16 + l15;
                float bias = b1[c];
                #pragma unroll
                for (int mt = 0; mt < 4; ++mt)
                    #pragma unroll
                    for (int j = 0; j < 4; ++j) {
                        int r = mt * 16 + lg * 4 + j;
                        sm_h1[r * H1_S + c] =
                            (__bf16)fmaxf(acc[ti][mt][j] + bias, 0.0f);
                    }
            }
        }
    }
    __syncthreads();

    // ---------------- Layer 2: h2 = relu(h1 @ W2^T + b2) ----------------------
    // M=64, N=304 (19 nt), K=416 (13 ksteps; A zero-padded, B addr-clamped)
    f32x4 acc2[3][4];
    #pragma unroll
    for (int a = 0; a < 3; ++a)
        #pragma unroll
        for (int b = 0; b < 4; ++b) acc2[a][b] = (f32x4){0.f, 0.f, 0.f, 0.f};

    for (int ks = 0; ks < 13; ++ks) {
        const int kb = ks * 32 + lg * 8;
        bf16x8 afr[4];
        #pragma unroll
        for (int mt = 0; mt < 4; ++mt)
            afr[mt] = *reinterpret_cast<const bf16x8*>(
                &sm_h1[(mt * 16 + l15) * H1_S + kb]);
        const int kbw = (kb >= 400) ? 0 : kb;    // A is zero there; clamp B addr
        #pragma unroll
        for (int ti = 0; ti < 3; ++ti) {
            int nt = w + ti * 8;
            if (nt < 19) {
                int cc = nt * 16 + l15;
                if (cc >= 300) cc = 299;         // results discarded
                bf16x8 bfr;
                if constexpr (WBF16) {
                    bfr = *reinterpret_cast<const bf16x8*>(
                        W2b + (size_t)cc * H1N + kbw);
                } else {
                    const float4* wp = reinterpret_cast<const float4*>(
                        W2f + (size_t)cc * H1N + kbw);
                    bfr = cvt8(wp[0], wp[1]);
                }
                #pragma unroll
                for (int mt = 0; mt < 4; ++mt)
                    acc2[ti][mt] = __builtin_amdgcn_mfma_f32_16x16x32_bf16(
                        afr[mt], bfr, acc2[ti][mt], 0, 0, 0);
            }
        }
    }
    __syncthreads();   // all h1 reads done; safe to overlay core

    // core = [relu(h2) | cr | la | zeros..319], Whead staged at rows 64..66
    #pragma unroll
    for (int ti = 0; ti < 3; ++ti) {
        int nt = w + ti * 8;
        if (nt < 19) {
            int c = nt * 16 + l15;
            if (c < 300) {
                float bias = b2[c];
                #pragma unroll
                for (int mt = 0; mt < 4; ++mt)
                    #pragma unroll
                    for (int j = 0; j < 4; ++j) {
                        int r = mt * 16 + lg * 4 + j;
                        sm_core[r * CO_S + c] =
                            (__bf16)fmaxf(acc2[ti][mt][j] + bias, 0.0f);
                    }
            }
        }
    }
    if (tid < 64) {
        int r = row0 + tid;
        float cr = fminf(fmaxf(reward[r], -1.0f), 1.0f);
        sm_core[tid * CO_S + 300] = (__bf16)cr;
        sm_core[tid * CO_S + 301] = (__bf16)(float)last_action[r];
        #pragma unroll
        for (int k = 302; k < 320; ++k) sm_core[tid * CO_S + k] = (__bf16)0.0f;
    }
    for (int i = tid; i < 3 * CO_S; i += 512) {  // Whead: rows 0..2, cols 0..327
        int ro = i / CO_S, k = i - ro * CO_S;
        float v = (k < CORE) ? ((ro < 2) ? Wp[ro * CORE + k] : Wb[k]) : 0.0f;
        sm_core[(WH_R + ro) * CO_S + k] = (__bf16)v;
    }
    __syncthreads();

    // ---------------- Head via MFMA: [64 x 320] @ Whead^T --------------------
    if (w < 4) {
        f32x4 hac = (f32x4){0.f, 0.f, 0.f, 0.f};
        #pragma unroll
        for (int ks = 0; ks < 10; ++ks) {
            int kb = ks * 32 + lg * 8;
            bf16x8 afr = *reinterpret_cast<const bf16x8*>(
                &sm_core[(w * 16 + l15) * CO_S + kb]);
            bf16x8 bfr = *reinterpret_cast<const bf16x8*>(
                &sm_core[(WH_R + l15) * CO_S + kb]);
            hac = __builtin_amdgcn_mfma_f32_16x16x32_bf16(afr, bfr, hac, 0, 0, 0);
        }
        if (l15 < 3) {
            float bias = (l15 < 2) ? bp[l15] : bb[0];
            #pragma unroll
            for (int j = 0; j < 4; ++j) {
                float v = hac[j] + bias;
                if (l15 < 2) v = 1.0f / (1.0f + __expf(-v));
                sm_res[w * 16 + lg * 4 + j][l15] = v;
            }
        }
    }
    __syncthreads();

    if (tid < 64) {
        int r = row0 + tid;
        float mu = sm_res[tid][0], sg = sm_res[tid][1], bl = sm_res[tid][2];
        float4 o4 = make_float4(mu, sg, bl, fmaf(sg, eps[r], mu));
        *reinterpret_cast<float4*>(out + (size_t)r * 4) = o4;
    }
}

extern "C" void kernel_launch(void* const* d_in, const int* in_sizes, int n_in,
                              void* d_out, int out_size, void* d_ws, size_t ws_size,
                              hipStream_t stream) {
    const float* frame       = (const float*)d_in[0];
    const float* reward      = (const float*)d_in[1];
    const int*   last_action = (const int*)  d_in[2];
    const float* eps         = (const float*)d_in[3];
    const float* W1          = (const float*)d_in[4];
    const float* b1          = (const float*)d_in[5];
    const float* W2          = (const float*)d_in[6];
    const float* b2          = (const float*)d_in[7];
    const float* Wp          = (const float*)d_in[8];
    const float* bp          = (const float*)d_in[9];
    const float* Wb          = (const float*)d_in[10];
    const float* bb          = (const float*)d_in[11];
    float* out = (float*)d_out;

    const size_t wbytes = (size_t)(H1N * OBS + H2N * H1N) * 2;   // 649600
    dim3 grid(TBR / 64);   // 2048 blocks

    if (ws_size >= wbytes) {
        __bf16* wsb = (__bf16*)d_ws;
        int nconv = (H1N * OBS + H2N * H1N) / 8;                 // 40600
        conv_weights<<<(nconv + 255) / 256, 256, 0, stream>>>(W1, W2, wsb);
        autoprune_mfma<true><<<grid, 512, 0, stream>>>(
            frame, reward, last_action, eps, W1, b1, W2, b2, Wp, bp, Wb, bb,
            (const __bf16*)wsb, (const __bf16*)(wsb + H1N * OBS), out);
    } else {
        autoprune_mfma<false><<<grid, 512, 0, stream>>>(
            frame, reward, last_action, eps, W1, b1, W2, b2, Wp, bp, Wb, bb,
            (const __bf16*)nullptr, (const __bf16*)nullptr, out);
    }
}